// Round 1
// baseline (229.968 us; speedup 1.0000x reference)
//
#include <hip/hip_runtime.h>

// Morton decode: out[b,c,i,j] = x[b,c,ij] where i = odd bits of ij, j = even bits.
// B=8, C=64, L=65536 (S=256), fp32.
//
// Structure: a 64x64 (i,j) output tile == a contiguous 4096-float source range
// (interleaving 6 bits of i with 6 bits of j fills source bits 0..11).
// One block = one tile: perfectly coalesced float4 source loads; each float4 is
// a 2x2 output quad (source bits 0,1 = (j0,i0)); two float2 stores per quad.
// Per wave, 8 lanes fully cover each 64B output cacheline -> no wasted bytes.

__device__ __forceinline__ unsigned compact1by1(unsigned x) {
    // keep even-position bits of x, compact them to the low bits
    x &= 0x55555555u;
    x = (x ^ (x >> 1)) & 0x33333333u;
    x = (x ^ (x >> 2)) & 0x0f0f0f0fu;
    x = (x ^ (x >> 4)) & 0x00ff00ffu;
    x = (x ^ (x >> 8)) & 0x0000ffffu;
    return x;
}

__global__ __launch_bounds__(256) void Morton_decode_69312182223578_kernel(
        const float* __restrict__ x, float* __restrict__ out) {
    const unsigned b    = blockIdx.x;
    const unsigned bc   = b >> 4;       // image index 0..511 (B*C)
    const unsigned tile = b & 15u;      // 4x4 grid of 64x64 tiles
    const unsigned ti   = tile >> 2;
    const unsigned tj   = tile & 3u;
    // morton(ti, tj): tj bits at even positions, ti bits at odd positions (2 bits each)
    const unsigned tile_morton =
        (tj & 1u) | ((ti & 1u) << 1) | ((tj >> 1) << 2) | ((ti >> 1) << 3);

    const float4* __restrict__ src =
        (const float4*)(x + (size_t)bc * 65536u + ((size_t)tile_morton << 12));
    float* __restrict__ dst = out + (size_t)bc * 65536u;

#pragma unroll
    for (int k = 0; k < 4; ++k) {
        const unsigned q = (unsigned)k * 256u + threadIdx.x;  // quad index 0..1023
        const float4 v = src[q];                               // coalesced 16B load
        const unsigned qj = compact1by1(q);        // even bits of q (5 bits)
        const unsigned qi = compact1by1(q >> 1);   // odd bits of q  (5 bits)
        const unsigned i = ti * 64u + 2u * qi;
        const unsigned j = tj * 64u + 2u * qj;
        float* p = dst + (size_t)i * 256u + j;
        // source r bits: bit0=j0, bit1=i0 -> (v.x,v.y) = row i, (v.z,v.w) = row i+1
        *(float2*)p         = make_float2(v.x, v.y);
        *(float2*)(p + 256) = make_float2(v.z, v.w);
    }
}

extern "C" void kernel_launch(void* const* d_in, const int* in_sizes, int n_in,
                              void* d_out, int out_size, void* d_ws, size_t ws_size,
                              hipStream_t stream) {
    const float* x = (const float*)d_in[0];
    float* out = (float*)d_out;
    // 512 images * 16 tiles = 8192 blocks
    Morton_decode_69312182223578_kernel<<<8192, 256, 0, stream>>>(x, out);
}

// Round 3
// 229.277 us; speedup vs baseline: 1.0030x; 1.0030x over previous
//
#include <hip/hip_runtime.h>

// Morton decode: out[b,c,i,j] = x[b,c,ij], i = odd bits of ij, j = even bits.
// B=8, C=64, L=65536 (S=256), fp32.
//
// One block = one 64x64 output tile = one contiguous 16 KB source range.
// Each thread handles 4 consecutive quads (64 B contiguous source) = a 4x4
// output patch: 4 independent 16 B loads in flight (4x the MLP of R1's
// serialized loop), then 4 x 16 B nontemporal stores (one per output row).
// Per store instruction the wave covers 8 rows x 128 B fully-contiguous
// segments -> full cachelines, no write amplification.

typedef float f32x4 __attribute__((ext_vector_type(4)));

__device__ __forceinline__ unsigned compact1by1(unsigned x) {
    // compact the even-position bits of x into the low bits
    x &= 0x55555555u;
    x = (x ^ (x >> 1)) & 0x33333333u;
    x = (x ^ (x >> 2)) & 0x0f0f0f0fu;
    x = (x ^ (x >> 4)) & 0x00ff00ffu;
    return x;
}

__global__ __launch_bounds__(256) void Morton_decode_69312182223578_kernel(
        const float* __restrict__ x, float* __restrict__ out) {
    const unsigned b    = blockIdx.x;
    const unsigned bc   = b >> 4;       // image index 0..511 (B*C)
    const unsigned tile = b & 15u;      // 4x4 grid of 64x64 tiles
    const unsigned ti   = tile >> 2;
    const unsigned tj   = tile & 3u;
    // morton(ti, tj): tj bits even positions, ti bits odd positions
    const unsigned tile_morton =
        (tj & 1u) | ((ti & 1u) << 1) | ((tj >> 1) << 2) | ((ti >> 1) << 3);

    const f32x4* __restrict__ src =
        (const f32x4*)(x + (size_t)bc * 65536u + ((size_t)tile_morton << 12));
    const unsigned t = threadIdx.x;

    // 4 independent 16 B loads; 64 B contiguous per lane, all outstanding.
    const f32x4 v0 = src[4u * t + 0u];
    const f32x4 v1 = src[4u * t + 1u];
    const f32x4 v2 = src[4u * t + 2u];
    const f32x4 v3 = src[4u * t + 3u];

    // Quad group g = t: t bits (0..7) = j2,i2,j3,i3,j4,i4,j5,i5
    const unsigned Jh = compact1by1(t);        // j2..j5 (4 bits)
    const unsigned Ih = compact1by1(t >> 1);   // i2..i5 (4 bits)
    const unsigned i0 = ti * 64u + 4u * Ih;
    const unsigned j0 = tj * 64u + 4u * Jh;

    // Quad m bits: (j1, i1).  m=0:(r0,c0) m=1:(r0,c2) m=2:(r2,c0) m=3:(r2,c2)
    // Within a quad: .x=(r,c) .y=(r,c+1) .z=(r+1,c) .w=(r+1,c+1)
    const f32x4 r0 = {v0.x, v0.y, v1.x, v1.y};
    const f32x4 r1 = {v0.z, v0.w, v1.z, v1.w};
    const f32x4 r2 = {v2.x, v2.y, v3.x, v3.y};
    const f32x4 r3 = {v2.z, v2.w, v3.z, v3.w};

    float* p = out + (size_t)bc * 65536u + (size_t)i0 * 256u + j0;
    __builtin_nontemporal_store(r0, (f32x4*)(p));
    __builtin_nontemporal_store(r1, (f32x4*)(p + 256));
    __builtin_nontemporal_store(r2, (f32x4*)(p + 512));
    __builtin_nontemporal_store(r3, (f32x4*)(p + 768));
}

extern "C" void kernel_launch(void* const* d_in, const int* in_sizes, int n_in,
                              void* d_out, int out_size, void* d_ws, size_t ws_size,
                              hipStream_t stream) {
    const float* x = (const float*)d_in[0];
    float* out = (float*)d_out;
    // 512 images * 16 tiles = 8192 blocks, one pass per block (no loop)
    Morton_decode_69312182223578_kernel<<<8192, 256, 0, stream>>>(x, out);
}